// Round 6
// baseline (109.075 us; speedup 1.0000x reference)
//
#include <hip/hip_runtime.h>

#define NN 100000
#define NE 1600000
#define TT 12
#define HH 32
#define NB 391          // coarse buckets of 256 nodes (node bucket = d >> 8)
#define BSH 8
#define GCS 16          // gcursor stride (ints) = one 64B line per cursor
#define CHUNK 4096      // edges per scatter block
#define SORTCAP 4800    // records per sort block (mean 4096, sigma 64 -> +11 sigma)
#define LOG2E 1.4426950408889634f

// ---------------- workspace layout (4-byte units), ~20.0 MB ----------------
// [0, 400)             : bstart[392]
// [400, 800)           : cnt[391]      (zeroed by k_zero)
// [800, 816)           : done flag     (zeroed by k_zero)
// [816, 7072)          : gcursor (x16 padded)
// [7072, 107088)       : nodebase[100001]
// [107088, 207088)     : dinv (float)
// [207104, 1807104)    : xp (float[NN][16]) = dinv[n]*x[n], 64B-aligned rows
// [1807104, 5007104)   : rec (int2[NE]); byte off 7228416 % 8 == 0
// [5007104, 5007248)   : P params: Az[32],Bz[32],Ah2[32],Bh2[32],probs[12]
//                        (gate params pre-scaled by log2e for raw v_exp_f32)
// NOTE: the 41us __amd_rocclr_fillBufferAligned dispatches in rocprof are the
// harness's 256MiB workspace re-poison (reset phase) — NOT in the timed window.

__global__ __launch_bounds__(512) void k_zero(int* __restrict__ ws32) {
    int t = threadIdx.x;
    if (t < 416) ws32[400 + t] = 0;   // cnt[391] + pad + done
}

// Bucket histogram; the LAST block to finish (global done counter) then does
// the bucket scan + gate-param folding in the same launch.
// NOTE: per-edge GLOBAL float atomics are catastrophic on gfx950 (R2: 90us,
// WRITE_SIZE == 1.6M x 32B -> uncached fabric writes). LDS atomics only.
__global__ __launch_bounds__(256) void k_pre(const int* __restrict__ ei,
                                             int* __restrict__ cnt,
                                             int* __restrict__ done,
                                             int* __restrict__ bstart,
                                             int* __restrict__ gcursor,
                                             const float* __restrict__ czw, const float* __restrict__ czb,
                                             const float* __restrict__ lzw, const float* __restrict__ lzb,
                                             const float* __restrict__ chw, const float* __restrict__ chb,
                                             const float* __restrict__ lhw, const float* __restrict__ lhb,
                                             const float* __restrict__ att, float* __restrict__ P) {
    __shared__ int h[NB];
    __shared__ int lastFlag;
    int b = blockIdx.x, t = threadIdx.x;
    for (int j = t; j < NB; j += 256) h[j] = 0;
    __syncthreads();
    const int EPB = NE / 256;  // 6250
    int e0 = b * EPB;
    for (int k = t; k < EPB; k += 256) atomicAdd(&h[ei[NE + e0 + k] >> BSH], 1);
    __syncthreads();
    for (int j = t; j < NB; j += 256) if (h[j]) atomicAdd(&cnt[j], h[j]);
    // ---- last-done block performs the scan + params ----
    if (t == 0) {
        __threadfence();
        int r = atomicAdd(done, 1);
        lastFlag = (r == (int)gridDim.x - 1);
    }
    __syncthreads();
    if (!lastFlag) return;
    // each thread owns 2 consecutive buckets (512 >= 391)
    int j0 = 2 * t;
    int c0 = 0, c1 = 0;
    if (j0 < NB)     c0 = atomicAdd(&cnt[j0], 0);      // device-scope load (skip stale L1)
    if (j0 + 1 < NB) c1 = atomicAdd(&cnt[j0 + 1], 0);
    int s = c0 + c1;
    __syncthreads();           // h[] reuse as scan buffer
    h[t] = s;
    __syncthreads();
    for (int o = 1; o < 256; o <<= 1) {
        int add = (t >= o) ? h[t - o] : 0;
        __syncthreads();
        h[t] += add;
        __syncthreads();
    }
    int e = h[t] - s;  // exclusive prefix over thread-pairs
    if (j0 < NB)     { bstart[j0] = e;     gcursor[j0 * GCS] = e; }
    e += c0;
    if (j0 + 1 < NB) { bstart[j0 + 1] = e; gcursor[(j0 + 1) * GCS] = e; }
    if (t == 0) bstart[NB] = NE;
    // ---- gate params (threads 0..31) ----
    if (t < HH) {
        int j = t;
        float az = 0.f, bz = 0.f, ah = 0.f, bh = 0.f;
        for (int k = 0; k < HH; ++k) {
            float lz = lzw[k * HH + j];
            float lh = lhw[k * HH + j];
            az = fmaf(czw[k], lz, az);
            bz = fmaf(czb[k], lz, bz);
            ah = fmaf(chw[k], lh, ah);
            bh = fmaf(chb[k], lh, bh);
        }
        // pre-scale by log2e so the hot loop uses raw v_exp_f32 (2^x)
        P[j]        = az * LOG2E;
        P[HH + j]   = (bz + lzb[j]) * LOG2E;
        P[2*HH + j] = 2.0f * LOG2E * ah;          // tanh(x) = f(2^(2x*log2e))
        P[3*HH + j] = 2.0f * LOG2E * (bh + lhb[j]);
    }
    if (t == 0) {
        float m = -1e30f;
        for (int q = 0; q < TT; ++q) m = fmaxf(m, att[q]);
        float ex[TT]; float ssum = 0.f;
        for (int q = 0; q < TT; ++q) { ex[q] = expf(att[q] - m); ssum += ex[q]; }
        for (int q = 0; q < TT; ++q) P[4*HH + q] = ex[q] / ssum;
    }
}

// Chunk-local counting sort: bin 4096 edges in LDS, reserve per-bucket global
// runs (1 atomic per non-empty bucket), stream out so each cache line is
// written by one wave in one burst. rec.y = raw ew (dinv folded later).
__global__ __launch_bounds__(512) void k_scatter(const int* __restrict__ ei,
                                                 const float* __restrict__ ew,
                                                 int* __restrict__ gcursor,
                                                 int2* __restrict__ rec) {
    __shared__ int2 cbuf[CHUNK];                 // 32 KB
    __shared__ unsigned short bkt[CHUNK];        // 8 KB
    __shared__ int sc[512];
    __shared__ int cnt[NB], off[NB], cur[NB], gb[NB];
    int t = threadIdx.x;
    int base = blockIdx.x * CHUNK;
    int m = min(CHUNK, NE - base);
    for (int j = t; j < NB; j += 512) { cnt[j] = 0; cur[j] = 0; }
    __syncthreads();
    int dsts[8], srcs[8]; float ews[8];
#pragma unroll
    for (int i = 0; i < 8; ++i) {
        int k = t + i * 512;
        if (k < m) {
            int e = base + k;
            dsts[i] = ei[NE + e]; srcs[i] = ei[e]; ews[i] = ew[e];
            atomicAdd(&cnt[dsts[i] >> BSH], 1);
        }
    }
    __syncthreads();
    int v = (t < NB) ? cnt[t] : 0;
    sc[t] = v;
    __syncthreads();
    for (int o = 1; o < 512; o <<= 1) {
        int add = (t >= o) ? sc[t - o] : 0;
        __syncthreads();
        sc[t] += add;
        __syncthreads();
    }
    if (t < NB) {
        off[t] = sc[t] - v;
        gb[t] = v ? atomicAdd(&gcursor[t * GCS], v) : 0;
    }
    __syncthreads();
#pragma unroll
    for (int i = 0; i < 8; ++i) {
        int k = t + i * 512;
        if (k < m) {
            int b = dsts[i] >> BSH;
            int p = off[b] + atomicAdd(&cur[b], 1);
            // src in bits 0..16 (100000 < 2^17), node-local dst (d&255) in 17..24
            cbuf[p] = make_int2(srcs[i] | ((dsts[i] & 255) << 17), __float_as_int(ews[i]));
            bkt[p] = (unsigned short)b;
        }
    }
    __syncthreads();
    for (int k = t; k < m; k += 512) {
        int b = bkt[k];
        rec[gb[b] + (k - off[b])] = cbuf[k];
    }
}

// One block = one coarse bucket = 256 nodes. In-place sort to exact per-node
// order; computes dinv + nodebase via LDS atomics; pre-scales weight by
// dinv[dst]; ALSO builds the padded pre-scaled feature table
// xp[n][16] = dinv[n] * x[n][0..11] (one aligned 64B line per node).
__global__ __launch_bounds__(512) void k_sort(const int* __restrict__ bstart,
                                              int2* __restrict__ rec,
                                              int* __restrict__ nodebase,
                                              float* __restrict__ dinv,
                                              const float* __restrict__ x,
                                              float* __restrict__ xp) {
    __shared__ int2 buf[SORTCAP];                // 37.5 KB
    __shared__ int cnt[256], cur[256], sc[512];
    __shared__ float wsum[256], dvs[256];
    int blk = blockIdx.x, t = threadIdx.x;
    int g0 = bstart[blk], g1 = bstart[blk + 1];
    int m = min(g1 - g0, SORTCAP);
    if (t < 256) { cnt[t] = 0; wsum[t] = 0.f; }
    __syncthreads();
    for (int k = t; k < m; k += 512) {
        int2 r = rec[g0 + k];
        buf[k] = r;
        int loc = (r.x >> 17) & 255;
        atomicAdd(&cnt[loc], 1);
        atomicAdd(&wsum[loc], __int_as_float(r.y));
    }
    __syncthreads();
    int v = (t < 256) ? cnt[t] : 0;
    sc[t] = v;
    __syncthreads();
    for (int o = 1; o < 256; o <<= 1) {
        int add = (t >= o) ? sc[t - o] : 0;
        __syncthreads();
        sc[t] += add;
        __syncthreads();
    }
    if (t < 256) {
        int e = sc[t] - v;  // exclusive prefix
        cur[t] = e;
        float dv = rsqrtf(1.0f + wsum[t]);  // +1 = self loop
        dvs[t] = dv;
        int n = (blk << BSH) + t;
        if (n < NN) {
            dinv[n] = dv; nodebase[n] = g0 + e;
            // build padded pre-scaled feature line
            const float4* xr = (const float4*)(x + (long)n * TT);
            float4* xo = (float4*)(xp + ((long)n << 4));
            float4 v0 = xr[0], v1 = xr[1], v2 = xr[2];
            v0.x *= dv; v0.y *= dv; v0.z *= dv; v0.w *= dv;
            v1.x *= dv; v1.y *= dv; v1.z *= dv; v1.w *= dv;
            v2.x *= dv; v2.y *= dv; v2.z *= dv; v2.w *= dv;
            xo[0] = v0; xo[1] = v1; xo[2] = v2;
        }
    }
    if (blk == NB - 1 && t == 0) nodebase[NN] = NE;
    __syncthreads();
    for (int k = t; k < m; k += 512) {
        int2 r = buf[k];
        int loc = (r.x >> 17) & 255;
        int p = atomicAdd(&cur[loc], 1);
        float w2 = __int_as_float(r.y) * dvs[loc];  // fold dinv[dst] into weight
        rec[g0 + p] = make_int2(r.x & 0x1FFFF, __float_as_int(w2));
    }
}

// 8 lanes/node = 2 slots x 4 roles. Roles 0-2 of a slot load ONE float4
// quadrant each of the SAME 64B xp row in the SAME instruction -> the TA
// coalescer merges them into a single line transaction: 1 L2 request/edge
// vs 3 before (three back-to-back float4 loads thrash the 32KB L1 at 24+
// resident waves, so each instruction was a separate L2 line request —
// why k_fused sat at ~40us invariant to VALU/occupancy/footprint changes).
// Each lane accumulates only its 4-period quad; shfl_xor(4) slot-combine,
// then xor-1/2 quad exchange + unrolled selects rebuild a[12] per lane.
__global__ __launch_bounds__(512) void k_fused(const int* __restrict__ nodebase,
                                               const int2* __restrict__ rec,
                                               const float* __restrict__ dinv,
                                               const float* __restrict__ xp,
                                               const float* __restrict__ P,
                                               const float* __restrict__ hw,
                                               const float* __restrict__ hb,
                                               float* __restrict__ out) {
    int g = blockIdx.x * 512 + threadIdx.x;
    int n = g >> 3, sub = g & 7;
    if (n >= NN) return;
    int role = sub & 3, slot = sub >> 2;
    float q0[4] = {0.f, 0.f, 0.f, 0.f};
    // self-loop: slot-0 lanes of roles 0..2 add their quad of dinv * xp[n]
    if (slot == 0 && role < 3) {
        float di = dinv[n];
        const float4* xr = (const float4*)(xp + ((long)n << 4));
        float4 v = xr[role];
        q0[0] = di * v.x; q0[1] = di * v.y; q0[2] = di * v.z; q0[3] = di * v.w;
    }
    int k0 = nodebase[n], k1 = nodebase[n + 1];
    for (int k = k0 + slot; k < k1; k += 2) {
        if (role < 3) {
            int2 r = rec[k];
            float c = __int_as_float(r.y);  // = ew * dinv[dst]; dinv[src] in xp
            const float4* xs = (const float4*)(xp + ((long)r.x << 4));
            float4 v = xs[role];            // 1 instr; 3 roles share the 64B line
            q0[0] = fmaf(c, v.x, q0[0]); q0[1] = fmaf(c, v.y, q0[1]);
            q0[2] = fmaf(c, v.z, q0[2]); q0[3] = fmaf(c, v.w, q0[3]);
        }
    }
    // combine slots, then exchange quads across roles (xor group {0,1,2,3})
    float q1[4], q2[4], q3[4];
#pragma unroll
    for (int i = 0; i < 4; ++i) {
        q0[i] += __shfl_xor(q0[i], 4);   // slot combine (role preserved)
        q1[i]  = __shfl_xor(q0[i], 1);   // quad of role^1
        q2[i]  = __shfl_xor(q0[i], 2);   // quad of role^2
        q3[i]  = __shfl_xor(q1[i], 2);   // quad of role^3
    }
    // a[4t+i] = quad t = data held by role t = q_{t ^ role}; t in {0,1,2}
    // (role-3 lanes hold zero quads; sel==t^role==3 only selects ANOTHER
    // lane's valid data, never a zero quad — mapping is closed and correct)
    float a[TT];
#pragma unroll
    for (int t = 0; t < 3; ++t) {
#pragma unroll
        for (int i = 0; i < 4; ++i) {
            int sel = t ^ role;
            a[4*t + i] = (sel == 0) ? q0[i] : (sel == 1) ? q1[i]
                       : (sel == 2) ? q2[i] : q3[i];
        }
    }
    // --- epilogue: gates + attention + head, 4 hidden channels per lane ---
    float p[TT];
#pragma unroll
    for (int q = 0; q < TT; ++q) p[q] = P[4*HH + q];
    float o = 0.f;
#pragma unroll
    for (int jj = 0; jj < 4; ++jj) {
        int j = (jj << 3) + sub;
        float Az = P[j], Bz = P[HH + j], Ah2 = P[2*HH + j], Bh2 = P[3*HH + j];
        float w = hw[j];
        float acc = 0.f;
#pragma unroll
        for (int q = 0; q < TT; ++q) {
            float xz = fmaf(a[q], Az, Bz);                   // log2-domain
            float xh = fminf(fmaf(a[q], Ah2, Bh2), 115.f);   // keep eh finite
            float ez = __builtin_amdgcn_exp2f(xz);  // e^orig_xz
            float eh = __builtin_amdgcn_exp2f(xh);  // e^(2*orig_xh)
            float den = (1.f + ez) * (eh + 1.f);
            float num = eh - 1.f;
            acc = fmaf(p[q] * num, __builtin_amdgcn_rcpf(den), acc);
        }
        o = fmaf(fmaxf(acc, 0.f), w, o);
    }
    o += __shfl_xor(o, 1);
    o += __shfl_xor(o, 2);
    o += __shfl_xor(o, 4);
    if (sub == 0) out[n] = o + hb[0];
}

extern "C" void kernel_launch(void* const* d_in, const int* in_sizes, int n_in,
                              void* d_out, int out_size, void* d_ws, size_t ws_size,
                              hipStream_t stream) {
    const float* x    = (const float*)d_in[0];
    const int*   ei   = (const int*)d_in[1];
    const float* ew   = (const float*)d_in[2];
    const float* att  = (const float*)d_in[3];
    const float* czw  = (const float*)d_in[4];
    const float* czb  = (const float*)d_in[5];
    const float* lzw  = (const float*)d_in[6];
    const float* lzb  = (const float*)d_in[7];
    // conv_r / lin_r (d_in[8..11]) are mathematically dead: H=0 -> H*R=0, Z*H=0.
    const float* chw  = (const float*)d_in[12];
    const float* chb  = (const float*)d_in[13];
    const float* lhw  = (const float*)d_in[14];
    const float* lhb  = (const float*)d_in[15];
    const float* hw   = (const float*)d_in[16];
    const float* hb   = (const float*)d_in[17];
    float* out = (float*)d_out;

    int*  ws32     = (int*)d_ws;
    int*  bstart   = ws32;                     // 392 (pad to 400)
    int*  cnt      = ws32 + 400;               // 391 (pad to 400)
    int*  done     = ws32 + 800;               // 1 (pad to 16)
    int*  gcursor  = ws32 + 816;               // NB*GCS = 6256
    int*  nodebase = ws32 + 7072;              // 100001 (pad to 100016)
    float* dinv    = (float*)(ws32 + 107088);  // NN (pad to 207104 = 16-aligned)
    float* xp      = (float*)(ws32 + 207104);  // NN*16 floats, 64B-aligned rows
    int2* rec      = (int2*)(ws32 + 1807104);  // NE int2; byte off 7228416 % 8 == 0
    float* P       = (float*)(ws32 + 5007104); // 144

    k_zero<<<1, 512, 0, stream>>>(ws32);
    k_pre<<<256, 256, 0, stream>>>(ei, cnt, done, bstart, gcursor,
                                   czw, czb, lzw, lzb, chw, chb, lhw, lhb, att, P);
    k_scatter<<<(NE + CHUNK - 1) / CHUNK, 512, 0, stream>>>(ei, ew, gcursor, rec);
    k_sort<<<NB, 512, 0, stream>>>(bstart, rec, nodebase, dinv, x, xp);
    k_fused<<<(NN * 8 + 511) / 512, 512, 0, stream>>>(nodebase, rec, dinv, xp, P, hw, hb, out);
}

// Round 7
// 97.015 us; speedup vs baseline: 1.1243x; 1.1243x over previous
//
#include <hip/hip_runtime.h>

#define NN 100000
#define NE 1600000
#define TT 12
#define HH 32
#define NB 391          // coarse buckets of 256 nodes (node bucket = d >> 8)
#define BSH 8
#define GCS 16          // gcursor stride (ints) = one 64B line per cursor
#define CHUNK 4096      // edges per scatter block
#define SORTCAP 4800    // records per sort block (mean 4096, sigma 64 -> +11 sigma)
#define LOG2E 1.4426950408889634f

typedef unsigned int u32;

// ---------------- workspace layout (4-byte units), ~17 MB ----------------
// [0, 400)             : bstart[392]
// [400, 800)           : cnt[391]      (zeroed by k_zero)
// [800, 816)           : done flag     (zeroed by k_zero)
// [816, 7072)          : gcursor (x16 padded)
// [7072, 107088)       : nodebase[100001]
// [107088, 207088)     : dinv (float)
// [207104, 1007104)    : xpb (u32[NN][8]) = bf16x2-packed dinv[n]*x[n], 32B rows
//                        -> 3.2MB table FITS the 4MB per-XCD L2 (fp32 6.4MB didn't;
//                        k_fused has been pinned at FETCH/1.4TB/s in every round)
// [1007104, 4207104)   : rec (int2[NE])
// [4207104, 4207248)   : P params: Az[32],Bz[32],Ah2[32],Bh2[32],probs[12]
//                        (gate params pre-scaled by log2e for raw v_exp_f32)
// NOTE: the ~41us __amd_rocclr_fillBufferAligned dispatches in rocprof are the
// harness's 256MiB workspace re-poison (reset phase) — NOT in the timed window.

__global__ __launch_bounds__(512) void k_zero(int* __restrict__ ws32) {
    int t = threadIdx.x;
    if (t < 416) ws32[400 + t] = 0;   // cnt[391] + pad + done
}

// Bucket histogram; the LAST block to finish (global done counter) then does
// the bucket scan + gate-param folding in the same launch.
// NOTE: per-edge GLOBAL float atomics are catastrophic on gfx950 (R2: 90us,
// WRITE_SIZE == 1.6M x 32B -> uncached fabric writes). LDS atomics only.
__global__ __launch_bounds__(256) void k_pre(const int* __restrict__ ei,
                                             int* __restrict__ cnt,
                                             int* __restrict__ done,
                                             int* __restrict__ bstart,
                                             int* __restrict__ gcursor,
                                             const float* __restrict__ czw, const float* __restrict__ czb,
                                             const float* __restrict__ lzw, const float* __restrict__ lzb,
                                             const float* __restrict__ chw, const float* __restrict__ chb,
                                             const float* __restrict__ lhw, const float* __restrict__ lhb,
                                             const float* __restrict__ att, float* __restrict__ P) {
    __shared__ int h[NB];
    __shared__ int lastFlag;
    int b = blockIdx.x, t = threadIdx.x;
    for (int j = t; j < NB; j += 256) h[j] = 0;
    __syncthreads();
    const int EPB = NE / 256;  // 6250
    int e0 = b * EPB;
    for (int k = t; k < EPB; k += 256) atomicAdd(&h[ei[NE + e0 + k] >> BSH], 1);
    __syncthreads();
    for (int j = t; j < NB; j += 256) if (h[j]) atomicAdd(&cnt[j], h[j]);
    // ---- last-done block performs the scan + params ----
    if (t == 0) {
        __threadfence();
        int r = atomicAdd(done, 1);
        lastFlag = (r == (int)gridDim.x - 1);
    }
    __syncthreads();
    if (!lastFlag) return;
    // each thread owns 2 consecutive buckets (512 >= 391)
    int j0 = 2 * t;
    int c0 = 0, c1 = 0;
    if (j0 < NB)     c0 = atomicAdd(&cnt[j0], 0);      // device-scope load (skip stale L1)
    if (j0 + 1 < NB) c1 = atomicAdd(&cnt[j0 + 1], 0);
    int s = c0 + c1;
    __syncthreads();           // h[] reuse as scan buffer
    h[t] = s;
    __syncthreads();
    for (int o = 1; o < 256; o <<= 1) {
        int add = (t >= o) ? h[t - o] : 0;
        __syncthreads();
        h[t] += add;
        __syncthreads();
    }
    int e = h[t] - s;  // exclusive prefix over thread-pairs
    if (j0 < NB)     { bstart[j0] = e;     gcursor[j0 * GCS] = e; }
    e += c0;
    if (j0 + 1 < NB) { bstart[j0 + 1] = e; gcursor[(j0 + 1) * GCS] = e; }
    if (t == 0) bstart[NB] = NE;
    // ---- gate params (threads 0..31) ----
    if (t < HH) {
        int j = t;
        float az = 0.f, bz = 0.f, ah = 0.f, bh = 0.f;
        for (int k = 0; k < HH; ++k) {
            float lz = lzw[k * HH + j];
            float lh = lhw[k * HH + j];
            az = fmaf(czw[k], lz, az);
            bz = fmaf(czb[k], lz, bz);
            ah = fmaf(chw[k], lh, ah);
            bh = fmaf(chb[k], lh, bh);
        }
        // pre-scale by log2e so the hot loop uses raw v_exp_f32 (2^x)
        P[j]        = az * LOG2E;
        P[HH + j]   = (bz + lzb[j]) * LOG2E;
        P[2*HH + j] = 2.0f * LOG2E * ah;          // tanh(x) = f(2^(2x*log2e))
        P[3*HH + j] = 2.0f * LOG2E * (bh + lhb[j]);
    }
    if (t == 0) {
        float m = -1e30f;
        for (int q = 0; q < TT; ++q) m = fmaxf(m, att[q]);
        float ex[TT]; float ssum = 0.f;
        for (int q = 0; q < TT; ++q) { ex[q] = expf(att[q] - m); ssum += ex[q]; }
        for (int q = 0; q < TT; ++q) P[4*HH + q] = ex[q] / ssum;
    }
}

// Chunk-local counting sort: bin 4096 edges in LDS, reserve per-bucket global
// runs (1 atomic per non-empty bucket), stream out so each cache line is
// written by one wave in one burst. rec.y = raw ew (dinv folded later).
__global__ __launch_bounds__(512) void k_scatter(const int* __restrict__ ei,
                                                 const float* __restrict__ ew,
                                                 int* __restrict__ gcursor,
                                                 int2* __restrict__ rec) {
    __shared__ int2 cbuf[CHUNK];                 // 32 KB
    __shared__ unsigned short bkt[CHUNK];        // 8 KB
    __shared__ int sc[512];
    __shared__ int cnt[NB], off[NB], cur[NB], gb[NB];
    int t = threadIdx.x;
    int base = blockIdx.x * CHUNK;
    int m = min(CHUNK, NE - base);
    for (int j = t; j < NB; j += 512) { cnt[j] = 0; cur[j] = 0; }
    __syncthreads();
    int dsts[8], srcs[8]; float ews[8];
#pragma unroll
    for (int i = 0; i < 8; ++i) {
        int k = t + i * 512;
        if (k < m) {
            int e = base + k;
            dsts[i] = ei[NE + e]; srcs[i] = ei[e]; ews[i] = ew[e];
            atomicAdd(&cnt[dsts[i] >> BSH], 1);
        }
    }
    __syncthreads();
    int v = (t < NB) ? cnt[t] : 0;
    sc[t] = v;
    __syncthreads();
    for (int o = 1; o < 512; o <<= 1) {
        int add = (t >= o) ? sc[t - o] : 0;
        __syncthreads();
        sc[t] += add;
        __syncthreads();
    }
    if (t < NB) {
        off[t] = sc[t] - v;
        gb[t] = v ? atomicAdd(&gcursor[t * GCS], v) : 0;
    }
    __syncthreads();
#pragma unroll
    for (int i = 0; i < 8; ++i) {
        int k = t + i * 512;
        if (k < m) {
            int b = dsts[i] >> BSH;
            int p = off[b] + atomicAdd(&cur[b], 1);
            // src in bits 0..16 (100000 < 2^17), node-local dst (d&255) in 17..24
            cbuf[p] = make_int2(srcs[i] | ((dsts[i] & 255) << 17), __float_as_int(ews[i]));
            bkt[p] = (unsigned short)b;
        }
    }
    __syncthreads();
    for (int k = t; k < m; k += 512) {
        int b = bkt[k];
        rec[gb[b] + (k - off[b])] = cbuf[k];
    }
}

__device__ __forceinline__ u32 bfpack(float a, float b) {  // RNE bf16 pair
    u32 ua = __float_as_uint(a), ub = __float_as_uint(b);
    ua = (ua + 0x7FFFu + ((ua >> 16) & 1u)) >> 16;
    ub = (ub + 0x7FFFu + ((ub >> 16) & 1u)) >> 16;
    return ua | (ub << 16);
}

// One block = one coarse bucket = 256 nodes. In-place sort to exact per-node
// order; computes dinv + nodebase via LDS atomics; pre-scales weight by
// dinv[dst]; builds the bf16-packed feature table xpb[n][8 u32] =
// bf16(dinv[n]*x[n][0..11]) + pad, 32B-aligned rows (3.2MB, fits per-XCD L2).
__global__ __launch_bounds__(512) void k_sort(const int* __restrict__ bstart,
                                              int2* __restrict__ rec,
                                              int* __restrict__ nodebase,
                                              float* __restrict__ dinv,
                                              const float* __restrict__ x,
                                              u32* __restrict__ xpb) {
    __shared__ int2 buf[SORTCAP];                // 37.5 KB
    __shared__ int cnt[256], cur[256], sc[512];
    __shared__ float wsum[256], dvs[256];
    int blk = blockIdx.x, t = threadIdx.x;
    int g0 = bstart[blk], g1 = bstart[blk + 1];
    int m = min(g1 - g0, SORTCAP);
    if (t < 256) { cnt[t] = 0; wsum[t] = 0.f; }
    __syncthreads();
    for (int k = t; k < m; k += 512) {
        int2 r = rec[g0 + k];
        buf[k] = r;
        int loc = (r.x >> 17) & 255;
        atomicAdd(&cnt[loc], 1);
        atomicAdd(&wsum[loc], __int_as_float(r.y));
    }
    __syncthreads();
    int v = (t < 256) ? cnt[t] : 0;
    sc[t] = v;
    __syncthreads();
    for (int o = 1; o < 256; o <<= 1) {
        int add = (t >= o) ? sc[t - o] : 0;
        __syncthreads();
        sc[t] += add;
        __syncthreads();
    }
    if (t < 256) {
        int e = sc[t] - v;  // exclusive prefix
        cur[t] = e;
        float dv = rsqrtf(1.0f + wsum[t]);  // +1 = self loop
        dvs[t] = dv;
        int n = (blk << BSH) + t;
        if (n < NN) {
            dinv[n] = dv; nodebase[n] = g0 + e;
            const float4* xr = (const float4*)(x + (long)n * TT);
            float4 v0 = xr[0], v1 = xr[1], v2 = xr[2];
            uint4* xo = (uint4*)(xpb + ((long)n << 3));
            uint4 w0, w1;
            w0.x = bfpack(v0.x * dv, v0.y * dv);
            w0.y = bfpack(v0.z * dv, v0.w * dv);
            w0.z = bfpack(v1.x * dv, v1.y * dv);
            w0.w = bfpack(v1.z * dv, v1.w * dv);
            w1.x = bfpack(v2.x * dv, v2.y * dv);
            w1.y = bfpack(v2.z * dv, v2.w * dv);
            w1.z = 0u; w1.w = 0u;
            xo[0] = w0; xo[1] = w1;
        }
    }
    if (blk == NB - 1 && t == 0) nodebase[NN] = NE;
    __syncthreads();
    for (int k = t; k < m; k += 512) {
        int2 r = buf[k];
        int loc = (r.x >> 17) & 255;
        int p = atomicAdd(&cur[loc], 1);
        float w2 = __int_as_float(r.y) * dvs[loc];  // fold dinv[dst] into weight
        rec[g0 + p] = make_int2(r.x & 0x1FFFF, __float_as_int(w2));
    }
}

#define BLO(w) __uint_as_float((w) << 16)
#define BHI(w) __uint_as_float((w) & 0xFFFF0000u)

// 8 lanes per node, each lane walks every-8th edge (R5 structure — R6's
// role-split regressed: halved edge-MLP, no FETCH reduction). Per edge:
// 8B coalesced rec + one 32B bf16 row (16B + 8B loads). k_fused has been
// pinned at FETCH_SIZE / 1.4 TB/s (L2-miss wall) in every round; the bf16
// table (3.2MB) fits the 4MB per-XCD L2 so repeat-gathers (avg degree 16)
// become L2 hits instead of misses.
__global__ __launch_bounds__(512) void k_fused(const int* __restrict__ nodebase,
                                               const int2* __restrict__ rec,
                                               const float* __restrict__ dinv,
                                               const u32* __restrict__ xpb,
                                               const float* __restrict__ P,
                                               const float* __restrict__ hw,
                                               const float* __restrict__ hb,
                                               float* __restrict__ out) {
    int g = blockIdx.x * 512 + threadIdx.x;
    int n = g >> 3, sub = g & 7;
    if (n >= NN) return;
    float a[TT];
#pragma unroll
    for (int q = 0; q < TT; ++q) a[q] = 0.f;
    if (sub == 0) {
        float di = dinv[n];   // self term = dinv * (bf16 row)
        const uint4* xr = (const uint4*)(xpb + ((long)n << 3));
        uint4 h0 = xr[0];
        uint2 h1 = *(const uint2*)(xr + 1);
        a[0]  = di * BLO(h0.x); a[1]  = di * BHI(h0.x);
        a[2]  = di * BLO(h0.y); a[3]  = di * BHI(h0.y);
        a[4]  = di * BLO(h0.z); a[5]  = di * BHI(h0.z);
        a[6]  = di * BLO(h0.w); a[7]  = di * BHI(h0.w);
        a[8]  = di * BLO(h1.x); a[9]  = di * BHI(h1.x);
        a[10] = di * BLO(h1.y); a[11] = di * BHI(h1.y);
    }
    int k0 = nodebase[n], k1 = nodebase[n + 1];
    for (int k = k0 + sub; k < k1; k += 8) {
        int2 r = rec[k];
        float c = __int_as_float(r.y);  // = ew * dinv[dst]; dinv[src] in xpb
        const uint4* xs = (const uint4*)(xpb + ((long)r.x << 3));
        uint4 h0 = xs[0];                       // periods 0-7 (16B)
        uint2 h1 = *(const uint2*)(xs + 1);     // periods 8-11 (8B)
        a[0]  = fmaf(c, BLO(h0.x), a[0]);  a[1]  = fmaf(c, BHI(h0.x), a[1]);
        a[2]  = fmaf(c, BLO(h0.y), a[2]);  a[3]  = fmaf(c, BHI(h0.y), a[3]);
        a[4]  = fmaf(c, BLO(h0.z), a[4]);  a[5]  = fmaf(c, BHI(h0.z), a[5]);
        a[6]  = fmaf(c, BLO(h0.w), a[6]);  a[7]  = fmaf(c, BHI(h0.w), a[7]);
        a[8]  = fmaf(c, BLO(h1.x), a[8]);  a[9]  = fmaf(c, BHI(h1.x), a[9]);
        a[10] = fmaf(c, BLO(h1.y), a[10]); a[11] = fmaf(c, BHI(h1.y), a[11]);
    }
    // tree-reduce the 12 accumulators across the 8 lanes of this node
#pragma unroll
    for (int q = 0; q < TT; ++q) {
        float v = a[q];
        v += __shfl_xor(v, 1);
        v += __shfl_xor(v, 2);
        v += __shfl_xor(v, 4);
        a[q] = v;
    }
    // --- epilogue: gates + attention + head, 4 hidden channels per lane ---
    float p[TT];
#pragma unroll
    for (int q = 0; q < TT; ++q) p[q] = P[4*HH + q];
    float o = 0.f;
#pragma unroll
    for (int jj = 0; jj < 4; ++jj) {
        int j = (jj << 3) + sub;
        float Az = P[j], Bz = P[HH + j], Ah2 = P[2*HH + j], Bh2 = P[3*HH + j];
        float w = hw[j];
        float acc = 0.f;
#pragma unroll
        for (int q = 0; q < TT; ++q) {
            float xz = fmaf(a[q], Az, Bz);                   // log2-domain
            float xh = fminf(fmaf(a[q], Ah2, Bh2), 115.f);   // keep eh finite
            float ez = __builtin_amdgcn_exp2f(xz);  // e^orig_xz
            float eh = __builtin_amdgcn_exp2f(xh);  // e^(2*orig_xh)
            float den = (1.f + ez) * (eh + 1.f);
            float num = eh - 1.f;
            acc = fmaf(p[q] * num, __builtin_amdgcn_rcpf(den), acc);
        }
        o = fmaf(fmaxf(acc, 0.f), w, o);
    }
    o += __shfl_xor(o, 1);
    o += __shfl_xor(o, 2);
    o += __shfl_xor(o, 4);
    if (sub == 0) out[n] = o + hb[0];
}

extern "C" void kernel_launch(void* const* d_in, const int* in_sizes, int n_in,
                              void* d_out, int out_size, void* d_ws, size_t ws_size,
                              hipStream_t stream) {
    const float* x    = (const float*)d_in[0];
    const int*   ei   = (const int*)d_in[1];
    const float* ew   = (const float*)d_in[2];
    const float* att  = (const float*)d_in[3];
    const float* czw  = (const float*)d_in[4];
    const float* czb  = (const float*)d_in[5];
    const float* lzw  = (const float*)d_in[6];
    const float* lzb  = (const float*)d_in[7];
    // conv_r / lin_r (d_in[8..11]) are mathematically dead: H=0 -> H*R=0, Z*H=0.
    const float* chw  = (const float*)d_in[12];
    const float* chb  = (const float*)d_in[13];
    const float* lhw  = (const float*)d_in[14];
    const float* lhb  = (const float*)d_in[15];
    const float* hw   = (const float*)d_in[16];
    const float* hb   = (const float*)d_in[17];
    float* out = (float*)d_out;

    int*  ws32     = (int*)d_ws;
    int*  bstart   = ws32;                     // 392 (pad to 400)
    int*  cnt      = ws32 + 400;               // 391 (pad to 400)
    int*  done     = ws32 + 800;               // 1 (pad to 16)
    int*  gcursor  = ws32 + 816;               // NB*GCS = 6256
    int*  nodebase = ws32 + 7072;              // 100001 (pad to 100016)
    float* dinv    = (float*)(ws32 + 107088);  // NN (pad to 207104 = 32B-aligned)
    u32*  xpb      = (u32*)(ws32 + 207104);    // NN*8 u32, 32B rows (3.2MB)
    int2* rec      = (int2*)(ws32 + 1007104);  // NE int2
    float* P       = (float*)(ws32 + 4207104); // 144

    k_zero<<<1, 512, 0, stream>>>(ws32);
    k_pre<<<256, 256, 0, stream>>>(ei, cnt, done, bstart, gcursor,
                                   czw, czb, lzw, lzb, chw, chb, lhw, lhb, att, P);
    k_scatter<<<(NE + CHUNK - 1) / CHUNK, 512, 0, stream>>>(ei, ew, gcursor, rec);
    k_sort<<<NB, 512, 0, stream>>>(bstart, rec, nodebase, dinv, x, xpb);
    k_fused<<<(NN * 8 + 511) / 512, 512, 0, stream>>>(nodebase, rec, dinv, xpb, P, hw, hb, out);
}